// Round 1
// baseline (240.178 us; speedup 1.0000x reference)
//
#include <hip/hip_runtime.h>
#include <math.h>

#define B_  16
#define C_  256
#define H_  64
#define W_  64
#define HW_ 4096
#define K_  7
#define KK_ 49
#define CR_ 64   // C/4

// ---------------- K1: global average pool: pooled[b*C+c] ----------------
__global__ __launch_bounds__(256) void pool_kernel(const float* __restrict__ x,
                                                   float* __restrict__ pooled) {
    int bc = blockIdx.x;
    const float4* p4 = (const float4*)(x + (size_t)bc * HW_);
    float s = 0.f;
    for (int i = threadIdx.x; i < HW_ / 4; i += 256) {
        float4 v = p4[i];
        s += (v.x + v.y) + (v.z + v.w);
    }
#pragma unroll
    for (int off = 32; off > 0; off >>= 1) s += __shfl_down(s, off);
    __shared__ float red[4];
    if ((threadIdx.x & 63) == 0) red[threadIdx.x >> 6] = s;
    __syncthreads();
    if (threadIdx.x == 0)
        pooled[bc] = (red[0] + red[1] + red[2] + red[3]) * (1.f / HW_);
}

// ---------------- K2: h = gelu(pooled @ w1^T + b1), exact gelu ----------------
__global__ __launch_bounds__(64) void mlp_kernel(const float* __restrict__ pooled,
                                                 const float* __restrict__ w1,
                                                 const float* __restrict__ b1,
                                                 float* __restrict__ h) {
    int b = blockIdx.x;
    int r = threadIdx.x;   // 0..63
    __shared__ float pr[C_];
    for (int i = r; i < C_; i += 64) pr[i] = pooled[b * C_ + i];
    __syncthreads();
    float acc = b1[r];
    const float* wr = w1 + (size_t)r * C_;
    for (int c = 0; c < C_; c += 4) {
        float4 wv = *(const float4*)(wr + c);
        acc += pr[c] * wv.x + pr[c + 1] * wv.y + pr[c + 2] * wv.z + pr[c + 3] * wv.w;
    }
    // exact gelu: x * 0.5 * (1 + erf(x / sqrt(2)))
    h[b * CR_ + r] = 0.5f * acc * (1.f + erff(acc * 0.70710678118654752f));
}

// ---------------- K3: fused[b, m] = dw[m] + b2[m] + sum_r h[b,r] * w2[m,r] ----------------
// m = c*49 + ij, flat over 12544.  grid 49 x 256 threads (one thread per m).
__global__ __launch_bounds__(256) void genw_kernel(const float* __restrict__ h,
                                                   const float* __restrict__ w2,
                                                   const float* __restrict__ b2,
                                                   const float* __restrict__ dw,
                                                   float* __restrict__ fused) {
    __shared__ float hs[B_ * CR_];
    int m = blockIdx.x * 256 + threadIdx.x;   // < 12544 exactly
    for (int i = threadIdx.x; i < B_ * CR_; i += 256) hs[i] = h[i];
    float wrow[CR_];
    const float4* w4 = (const float4*)(w2 + (size_t)m * CR_);
#pragma unroll
    for (int i = 0; i < CR_ / 4; i++) {
        float4 v = w4[i];
        wrow[4 * i] = v.x; wrow[4 * i + 1] = v.y;
        wrow[4 * i + 2] = v.z; wrow[4 * i + 3] = v.w;
    }
    float base = b2[m] + dw[m];
    __syncthreads();
    for (int b = 0; b < B_; b++) {
        float acc = base;
        const float* hb = hs + b * CR_;
#pragma unroll
        for (int r = 0; r < CR_; r++) acc += hb[r] * wrow[r];
        fused[(size_t)b * (C_ * KK_) + m] = acc;
    }
}

// ---------------- K4: transpose pw_weight [o][c] -> Pt [c][o] ----------------
__global__ __launch_bounds__(256) void transpose_kernel(const float* __restrict__ P,
                                                        float* __restrict__ Pt) {
    __shared__ float t[32][33];
    int bx = blockIdx.x & 7, by = blockIdx.x >> 3;
    int tx = threadIdx.x & 31, ty = threadIdx.x >> 5;   // ty 0..7
#pragma unroll
    for (int i = 0; i < 4; i++) {
        int r = ty * 4 + i;
        t[r][tx] = P[(size_t)(by * 32 + r) * C_ + bx * 32 + tx];
    }
    __syncthreads();
#pragma unroll
    for (int i = 0; i < 4; i++) {
        int r = ty * 4 + i;
        Pt[(size_t)(bx * 32 + r) * C_ + by * 32 + tx] = t[tx][r];
    }
}

// ---------------- K5: per-(b,c) depthwise 7x7 conv, zero pad 3 ----------------
__global__ __launch_bounds__(256) void dw_kernel(const float* __restrict__ x,
                                                 const float* __restrict__ fused,
                                                 float* __restrict__ U) {
    int bc = blockIdx.x;   // b*C + c
    __shared__ float tile[70 * 70];
    __shared__ float wk[KK_];
    const float* xp = x + (size_t)bc * HW_;
    for (int i = threadIdx.x; i < 70 * 70; i += 256) tile[i] = 0.f;
    __syncthreads();
    for (int i = threadIdx.x; i < HW_; i += 256) {
        int r = i >> 6, c = i & 63;
        tile[(r + 3) * 70 + (c + 3)] = xp[i];
    }
    if (threadIdx.x < KK_) wk[threadIdx.x] = fused[(size_t)bc * KK_ + threadIdx.x];
    __syncthreads();
    float* up = U + (size_t)bc * HW_;
    for (int i = threadIdx.x; i < HW_; i += 256) {
        int r = i >> 6, c = i & 63;
        float acc = 0.f;
#pragma unroll
        for (int ki = 0; ki < K_; ki++) {
#pragma unroll
            for (int kj = 0; kj < K_; kj++) {
                acc += tile[(r + ki) * 70 + (c + kj)] * wk[ki * K_ + kj];
            }
        }
        up[i] = acc;
    }
}

// ---------------- K6: pointwise GEMM  Y[b] = P @ U[b]  (fp32 tiled) ----------------
// Pt is [c][o] (K-major).  Block tile 64o x 64p x 32k, 256 threads, 4x4 microtile.
__global__ __launch_bounds__(256) void pw_kernel(const float* __restrict__ Pt,
                                                 const float* __restrict__ U,
                                                 float* __restrict__ Y) {
    __shared__ float Ps[32][64];
    __shared__ float Us[32][64];
    const int b = blockIdx.z;
    const int o0 = blockIdx.y * 64;
    const int p0 = blockIdx.x * 64;
    const float* Ub = U + (size_t)b * C_ * HW_;
    const int tid = threadIdx.x;
    const int tx = tid & 15, ty = tid >> 4;
    float acc[4][4] = {};
    for (int k0 = 0; k0 < C_; k0 += 32) {
#pragma unroll
        for (int i = 0; i < 2; i++) {
            int f4 = tid + i * 256;
            int kl = f4 >> 4, cl = (f4 & 15) << 2;
            *(float4*)&Ps[kl][cl] = *(const float4*)(Pt + (size_t)(k0 + kl) * C_ + o0 + cl);
            *(float4*)&Us[kl][cl] = *(const float4*)(Ub + (size_t)(k0 + kl) * HW_ + p0 + cl);
        }
        __syncthreads();
#pragma unroll
        for (int k = 0; k < 32; k++) {
            float4 a = *(float4*)&Ps[k][ty << 2];
            float4 u = *(float4*)&Us[k][tx << 2];
            acc[0][0] += a.x * u.x; acc[0][1] += a.x * u.y;
            acc[0][2] += a.x * u.z; acc[0][3] += a.x * u.w;
            acc[1][0] += a.y * u.x; acc[1][1] += a.y * u.y;
            acc[1][2] += a.y * u.z; acc[1][3] += a.y * u.w;
            acc[2][0] += a.z * u.x; acc[2][1] += a.z * u.y;
            acc[2][2] += a.z * u.z; acc[2][3] += a.z * u.w;
            acc[3][0] += a.w * u.x; acc[3][1] += a.w * u.y;
            acc[3][2] += a.w * u.z; acc[3][3] += a.w * u.w;
        }
        __syncthreads();
    }
    float* yb = Y + (size_t)b * C_ * HW_ + (size_t)(o0 + (ty << 2)) * HW_ + p0 + (tx << 2);
#pragma unroll
    for (int i = 0; i < 4; i++)
        *(float4*)(yb + (size_t)i * HW_) = *(float4*)&acc[i][0];
}

extern "C" void kernel_launch(void* const* d_in, const int* in_sizes, int n_in,
                              void* d_out, int out_size, void* d_ws, size_t ws_size,
                              hipStream_t stream) {
    const float* x  = (const float*)d_in[0];
    const float* dw = (const float*)d_in[1];
    const float* pw = (const float*)d_in[2];
    const float* w1 = (const float*)d_in[3];
    const float* b1 = (const float*)d_in[4];
    const float* w2 = (const float*)d_in[5];
    const float* b2 = (const float*)d_in[6];
    float* out = (float*)d_out;

    float* ws     = (float*)d_ws;
    float* pooled = ws;                        // 4096
    float* h      = pooled + B_ * C_;          // 1024
    float* fused  = h + B_ * CR_;              // 200704
    float* Pt     = fused + B_ * C_ * KK_;     // 65536
    float* U      = Pt + C_ * C_;              // 16777216

    hipLaunchKernelGGL(pool_kernel, dim3(B_ * C_), dim3(256), 0, stream, x, pooled);
    hipLaunchKernelGGL(mlp_kernel, dim3(B_), dim3(64), 0, stream, pooled, w1, b1, h);
    hipLaunchKernelGGL(genw_kernel, dim3(49), dim3(256), 0, stream, h, w2, b2, dw, fused);
    hipLaunchKernelGGL(transpose_kernel, dim3(64), dim3(256), 0, stream, pw, Pt);
    hipLaunchKernelGGL(dw_kernel, dim3(B_ * C_), dim3(256), 0, stream, x, fused, U);
    hipLaunchKernelGGL(pw_kernel, dim3(64, 4, B_), dim3(256), 0, stream, Pt, U, out);
}

// Round 2
// 158.091 us; speedup vs baseline: 1.5192x; 1.5192x over previous
//
#include <hip/hip_runtime.h>
#include <math.h>
#include <stdint.h>

typedef __attribute__((ext_vector_type(8))) short short8;
typedef __attribute__((ext_vector_type(4))) float f32x4;

#define B_  16
#define C_  256
#define HW_ 4096
#define KK_ 49
#define CR_ 64

__device__ __forceinline__ ushort f2bf(float f) {
    union { float f; uint32_t u; } v; v.f = f;
    uint32_t r = (v.u + 0x7FFFu + ((v.u >> 16) & 1u)) >> 16;
    return (ushort)r;
}
__device__ __forceinline__ float bflo(uint32_t w) { union { uint32_t u; float f; } v; v.u = w << 16; return v.f; }
__device__ __forceinline__ float bfhi(uint32_t w) { union { uint32_t u; float f; } v; v.u = w & 0xffff0000u; return v.f; }

// ---------------- K1: global average pool ----------------
__global__ __launch_bounds__(256) void pool_kernel(const float* __restrict__ x,
                                                   float* __restrict__ pooled) {
    int bc = blockIdx.x;
    const float4* p4 = (const float4*)(x + (size_t)bc * HW_);
    float s = 0.f;
    for (int i = threadIdx.x; i < HW_ / 4; i += 256) {
        float4 v = p4[i];
        s += (v.x + v.y) + (v.z + v.w);
    }
#pragma unroll
    for (int off = 32; off > 0; off >>= 1) s += __shfl_down(s, off);
    __shared__ float red[4];
    if ((threadIdx.x & 63) == 0) red[threadIdx.x >> 6] = s;
    __syncthreads();
    if (threadIdx.x == 0)
        pooled[bc] = (red[0] + red[1] + red[2] + red[3]) * (1.f / HW_);
}

// ---------------- K2: h = gelu(pooled @ w1^T + b1) ----------------
__global__ __launch_bounds__(64) void mlp_kernel(const float* __restrict__ pooled,
                                                 const float* __restrict__ w1,
                                                 const float* __restrict__ b1,
                                                 float* __restrict__ h) {
    int b = blockIdx.x;
    int r = threadIdx.x;
    __shared__ float pr[C_];
    for (int i = r; i < C_; i += 64) pr[i] = pooled[b * C_ + i];
    __syncthreads();
    float acc = b1[r];
    const float* wr = w1 + (size_t)r * C_;
    for (int c = 0; c < C_; c += 4) {
        float4 wv = *(const float4*)(wr + c);
        acc += pr[c] * wv.x + pr[c + 1] * wv.y + pr[c + 2] * wv.z + pr[c + 3] * wv.w;
    }
    h[b * CR_ + r] = 0.5f * acc * (1.f + erff(acc * 0.70710678118654752f));
}

// ---------------- K3: fused[b,m] = dw[m] + b2[m] + h[b,:] @ w2[m,:] ----------------
__global__ __launch_bounds__(256) void genw_kernel(const float* __restrict__ h,
                                                   const float* __restrict__ w2,
                                                   const float* __restrict__ b2,
                                                   const float* __restrict__ dw,
                                                   float* __restrict__ fused) {
    __shared__ float hs[B_ * CR_];
    int m = blockIdx.x * 256 + threadIdx.x;
    for (int i = threadIdx.x; i < B_ * CR_; i += 256) hs[i] = h[i];
    float wrow[CR_];
    const float4* w4 = (const float4*)(w2 + (size_t)m * CR_);
#pragma unroll
    for (int i = 0; i < CR_ / 4; i++) {
        float4 v = w4[i];
        wrow[4 * i] = v.x; wrow[4 * i + 1] = v.y;
        wrow[4 * i + 2] = v.z; wrow[4 * i + 3] = v.w;
    }
    float base = b2[m] + dw[m];
    __syncthreads();
    for (int b = 0; b < B_; b++) {
        float acc = base;
        const float* hb = hs + b * CR_;
#pragma unroll
        for (int r = 0; r < CR_; r++) acc += hb[r] * wrow[r];
        fused[(size_t)b * (C_ * KK_) + m] = acc;
    }
}

// ---------------- K4: pack pw_weight fp32 [o][c] -> Pa bf16 [o/16][c/8][16][8] ----------------
__global__ __launch_bounds__(256) void prep_kernel(const float* __restrict__ pw,
                                                   ushort* __restrict__ Pa) {
    int idx = blockIdx.x * 256 + threadIdx.x;   // 65536
    int o = idx >> 8, c = idx & 255;
    Pa[(size_t)(((o >> 4) * 32) + (c >> 3)) * 128 + (o & 15) * 8 + (c & 7)] = f2bf(pw[idx]);
}

// ---------------- K5: depthwise 7x7 conv, 8 channels/block, bf16 out ----------------
// Ug layout: [b][p>>4][c>>3][p&15][c&7] bf16
__global__ __launch_bounds__(256, 3) void dw_kernel(const float* __restrict__ x,
                                                    const float* __restrict__ fused,
                                                    ushort* __restrict__ Ug) {
    __shared__ ushort xs[8 * 38 * 72];   // 43776 B, ch-stride 2736 elems
    __shared__ float wsm[8 * 52];
    const int r0  = blockIdx.x * 32;
    const int cb  = blockIdx.y;
    const int b   = blockIdx.z;
    const int tid = threadIdx.x;
    const int c0  = cb * 8;

    for (int i = tid; i < 8 * 38 * 72; i += 256) {
        int ch = i / 2736;
        int r2 = i - ch * 2736;
        int row = r2 / 72;
        int col = r2 - row * 72;
        int gr = r0 + row - 3, gc = col - 3;
        float v = 0.f;
        if ((unsigned)gr < 64u && (unsigned)gc < 64u)
            v = x[(((size_t)b * C_ + c0 + ch) << 12) + (gr << 6) + gc];
        xs[i] = f2bf(v);
    }
    for (int i = tid; i < 8 * KK_; i += 256) {
        int ch = i / KK_, t = i - ch * KK_;
        wsm[ch * 52 + t] = fused[((size_t)b * C_ + c0 + ch) * KK_ + t];
    }
    __syncthreads();

    const int trow = tid >> 3;          // 0..31
    const int col8 = (tid & 7) << 3;    // 0..56

    for (int ch = 0; ch < 8; ch++) {
        float wk[49];
#pragma unroll
        for (int q = 0; q < 12; q++) {
            float4 w4 = *(const float4*)&wsm[ch * 52 + q * 4];
            wk[q * 4 + 0] = w4.x; wk[q * 4 + 1] = w4.y;
            wk[q * 4 + 2] = w4.z; wk[q * 4 + 3] = w4.w;
        }
        wk[48] = wsm[ch * 52 + 48];
        float acc[8] = {0.f, 0.f, 0.f, 0.f, 0.f, 0.f, 0.f, 0.f};
#pragma unroll
        for (int ki = 0; ki < 7; ki++) {
            const ushort* rp = &xs[ch * 2736 + (trow + ki) * 72 + col8];
            uint4 A  = *(const uint4*)rp;
            uint4 Bv = *(const uint4*)(rp + 8);
            float r[16];
            r[0]  = bflo(A.x);  r[1]  = bfhi(A.x);  r[2]  = bflo(A.y);  r[3]  = bfhi(A.y);
            r[4]  = bflo(A.z);  r[5]  = bfhi(A.z);  r[6]  = bflo(A.w);  r[7]  = bfhi(A.w);
            r[8]  = bflo(Bv.x); r[9]  = bfhi(Bv.x); r[10] = bflo(Bv.y); r[11] = bfhi(Bv.y);
            r[12] = bflo(Bv.z); r[13] = bfhi(Bv.z); r[14] = bflo(Bv.w); r[15] = bfhi(Bv.w);
#pragma unroll
            for (int kj = 0; kj < 7; kj++) {
#pragma unroll
                for (int j = 0; j < 8; j++)
                    acc[j] = fmaf(r[kj + j], wk[ki * 7 + kj], acc[j]);
            }
        }
        __syncthreads();   // everyone done reading xs[ch] before aliasing it
        uint32_t* os = (uint32_t*)&xs[ch * 2736];
        int px = trow * 64 + col8;
#pragma unroll
        for (int q = 0; q < 4; q++)
            os[(px >> 1) + q] = (uint32_t)f2bf(acc[2 * q]) | ((uint32_t)f2bf(acc[2 * q + 1]) << 16);
    }
    __syncthreads();
    // write-out: thread handles px tid*8 .. tid*8+7, 8 ch each -> 16B stores
    ushort rows[8][8];
#pragma unroll
    for (int ch = 0; ch < 8; ch++)
        *(uint4*)&rows[ch][0] = *(const uint4*)(&xs[ch * 2736] + tid * 8);
#pragma unroll
    for (int i = 0; i < 8; i++) {
        int p = r0 * 64 + tid * 8 + i;
        uint4 w;
        w.x = (uint32_t)rows[0][i] | ((uint32_t)rows[1][i] << 16);
        w.y = (uint32_t)rows[2][i] | ((uint32_t)rows[3][i] << 16);
        w.z = (uint32_t)rows[4][i] | ((uint32_t)rows[5][i] << 16);
        w.w = (uint32_t)rows[6][i] | ((uint32_t)rows[7][i] << 16);
        size_t e = ((((size_t)b * 256) + (p >> 4)) * 32 + cb) * 128 + (size_t)(p & 15) * 8;
        *(uint4*)(Ug + e) = w;
    }
}

// ---------------- K6: pointwise GEMM, bf16 MFMA. BM=256 BN=128 BK=64 ----------------
#define GLDS16(gp, lp) __builtin_amdgcn_global_load_lds(\
    (const __attribute__((address_space(1))) uint32_t*)(gp), \
    (__attribute__((address_space(3))) uint32_t*)(lp), 16, 0, 0)

__global__ __launch_bounds__(256, 2) void pw_kernel(const ushort* __restrict__ Pa,
                                                    const ushort* __restrict__ Ug,
                                                    float* __restrict__ Y) {
    __shared__ ushort As[16384];   // 256o x 64k: [obl(16)][kbl(8)][16][8]
    __shared__ ushort Bs[8192];    // 128p x 64k: [pgl(8)][kbl(8)][16][8]
    const int pb   = blockIdx.x;   // 0..31
    const int b    = blockIdx.y;
    const int tid  = threadIdx.x;
    const int w    = tid >> 6;
    const int lane = tid & 63;
    const int oi   = lane & 15;
    const int kq   = lane >> 4;    // 0..3

    f32x4 acc[4][8];
#pragma unroll
    for (int mi = 0; mi < 4; mi++)
#pragma unroll
        for (int ni = 0; ni < 8; ni++)
            acc[mi][ni] = (f32x4){0.f, 0.f, 0.f, 0.f};

    const size_t ubase = (((size_t)b * 256) + (size_t)pb * 8) * 32 * 128;

    for (int kk = 0; kk < 4; kk++) {
        __syncthreads();
        for (int q = w; q < 48; q += 4) {
            const ushort* src; ushort* dst;
            if (q < 32) {
                int obl = q >> 1, half = q & 1;
                src = Pa + (obl * 32 + kk * 8) * 128 + half * 512;
                dst = As + obl * 1024 + half * 512;
            } else {
                int idx = q - 32, pgl = idx >> 1, half = idx & 1;
                src = Ug + ubase + ((size_t)pgl * 32 + kk * 8) * 128 + half * 512;
                dst = Bs + pgl * 1024 + half * 512;
            }
            GLDS16(src + lane * 8, dst);
        }
        asm volatile("s_waitcnt vmcnt(0)" ::: "memory");
        __syncthreads();

        const int abase = w * 4096 + kq * 128 + oi * 8;
        const int bbase = kq * 128 + oi * 8;
#pragma unroll
        for (int ks = 0; ks < 2; ks++) {
            short8 af[4], bf[8];
#pragma unroll
            for (int mi = 0; mi < 4; mi++)
                af[mi] = *(const short8*)&As[abase + mi * 1024 + ks * 512];
#pragma unroll
            for (int ni = 0; ni < 8; ni++)
                bf[ni] = *(const short8*)&Bs[bbase + ni * 1024 + ks * 512];
#pragma unroll
            for (int mi = 0; mi < 4; mi++)
#pragma unroll
                for (int ni = 0; ni < 8; ni++)
                    acc[mi][ni] = __builtin_amdgcn_mfma_f32_16x16x32_bf16(
                        af[mi], bf[ni], acc[mi][ni], 0, 0, 0);
        }
    }
    float* yb = Y + ((size_t)b << 20);
    const int p0 = pb * 128;
#pragma unroll
    for (int mi = 0; mi < 4; mi++) {
#pragma unroll
        for (int ni = 0; ni < 8; ni++) {
            int p = p0 + ni * 16 + oi;
#pragma unroll
            for (int r = 0; r < 4; r++) {
                int o = w * 64 + mi * 16 + kq * 4 + r;
                yb[(size_t)o * HW_ + p] = acc[mi][ni][r];
            }
        }
    }
}

extern "C" void kernel_launch(void* const* d_in, const int* in_sizes, int n_in,
                              void* d_out, int out_size, void* d_ws, size_t ws_size,
                              hipStream_t stream) {
    const float* x  = (const float*)d_in[0];
    const float* dw = (const float*)d_in[1];
    const float* pw = (const float*)d_in[2];
    const float* w1 = (const float*)d_in[3];
    const float* b1 = (const float*)d_in[4];
    const float* w2 = (const float*)d_in[5];
    const float* b2 = (const float*)d_in[6];
    float* out = (float*)d_out;

    char* ws = (char*)d_ws;
    float*  pooled = (float*)(ws);                    // 16384 B
    float*  h      = (float*)(ws + 16384);            // 4096 B
    float*  fused  = (float*)(ws + 20480);            // 802816 B
    ushort* Pa     = (ushort*)(ws + 823296);          // 131072 B
    ushort* Ug     = (ushort*)(ws + 1048576);         // 33554432 B

    hipLaunchKernelGGL(pool_kernel, dim3(B_ * C_), dim3(256), 0, stream, x, pooled);
    hipLaunchKernelGGL(mlp_kernel,  dim3(B_), dim3(64), 0, stream, pooled, w1, b1, h);
    hipLaunchKernelGGL(genw_kernel, dim3(49), dim3(256), 0, stream, h, w2, b2, dw, fused);
    hipLaunchKernelGGL(prep_kernel, dim3(256), dim3(256), 0, stream, pw, Pa);
    hipLaunchKernelGGL(dw_kernel,   dim3(2, 32, B_), dim3(256), 0, stream, x, fused, Ug);
    hipLaunchKernelGGL(pw_kernel,   dim3(32, B_), dim3(256), 0, stream, Pa, Ug, out);
}

// Round 3
// 107.967 us; speedup vs baseline: 2.2246x; 1.4643x over previous
//
#include <hip/hip_runtime.h>
#include <math.h>
#include <stdint.h>

typedef __attribute__((ext_vector_type(8))) short short8;
typedef __attribute__((ext_vector_type(4))) float f32x4;

#define B_  16
#define C_  256
#define HW_ 4096
#define KK_ 49
#define CR_ 64

__device__ __forceinline__ ushort f2bf(float f) {
    union { float f; uint32_t u; } v; v.f = f;
    uint32_t r = (v.u + 0x7FFFu + ((v.u >> 16) & 1u)) >> 16;
    return (ushort)r;
}

// ---------------- K1: global average pool ----------------
__global__ __launch_bounds__(256) void pool_kernel(const float* __restrict__ x,
                                                   float* __restrict__ pooled) {
    int bc = blockIdx.x;
    const float4* p4 = (const float4*)(x + (size_t)bc * HW_);
    float s = 0.f;
    for (int i = threadIdx.x; i < HW_ / 4; i += 256) {
        float4 v = p4[i];
        s += (v.x + v.y) + (v.z + v.w);
    }
#pragma unroll
    for (int off = 32; off > 0; off >>= 1) s += __shfl_down(s, off);
    __shared__ float red[4];
    if ((threadIdx.x & 63) == 0) red[threadIdx.x >> 6] = s;
    __syncthreads();
    if (threadIdx.x == 0)
        pooled[bc] = (red[0] + red[1] + red[2] + red[3]) * (1.f / HW_);
}

// ---------------- K2: h = gelu(pooled @ w1^T + b1) ----------------
__global__ __launch_bounds__(64) void mlp_kernel(const float* __restrict__ pooled,
                                                 const float* __restrict__ w1,
                                                 const float* __restrict__ b1,
                                                 float* __restrict__ h) {
    int b = blockIdx.x;
    int r = threadIdx.x;
    __shared__ float pr[C_];
    for (int i = r; i < C_; i += 64) pr[i] = pooled[b * C_ + i];
    __syncthreads();
    float acc = b1[r];
    const float* wr = w1 + (size_t)r * C_;
    for (int c = 0; c < C_; c += 4) {
        float4 wv = *(const float4*)(wr + c);
        acc += pr[c] * wv.x + pr[c + 1] * wv.y + pr[c + 2] * wv.z + pr[c + 3] * wv.w;
    }
    h[b * CR_ + r] = 0.5f * acc * (1.f + erff(acc * 0.70710678118654752f));
}

// ---------------- K3: fused[b,m] = dw[m] + b2[m] + h[b,:] @ w2[m,:] ----------------
__global__ __launch_bounds__(256) void genw_kernel(const float* __restrict__ h,
                                                   const float* __restrict__ w2,
                                                   const float* __restrict__ b2,
                                                   const float* __restrict__ dw,
                                                   float* __restrict__ fused) {
    __shared__ float hs[B_ * CR_];
    int m = blockIdx.x * 256 + threadIdx.x;
    for (int i = threadIdx.x; i < B_ * CR_; i += 256) hs[i] = h[i];
    float wrow[CR_];
    const float4* w4 = (const float4*)(w2 + (size_t)m * CR_);
#pragma unroll
    for (int i = 0; i < CR_ / 4; i++) {
        float4 v = w4[i];
        wrow[4 * i] = v.x; wrow[4 * i + 1] = v.y;
        wrow[4 * i + 2] = v.z; wrow[4 * i + 3] = v.w;
    }
    float base = b2[m] + dw[m];
    __syncthreads();
    for (int b = 0; b < B_; b++) {
        float acc = base;
        const float* hb = hs + b * CR_;
#pragma unroll
        for (int r = 0; r < CR_; r++) acc += hb[r] * wrow[r];
        fused[(size_t)b * (C_ * KK_) + m] = acc;
    }
}

// ---------------- K4: pack pw_weight fp32 [o][c] -> Pa bf16 [o/16][c/8][16][8] ----------------
__global__ __launch_bounds__(256) void prep_kernel(const float* __restrict__ pw,
                                                   ushort* __restrict__ Pa) {
    int idx = blockIdx.x * 256 + threadIdx.x;   // 65536
    int o = idx >> 8, c = idx & 255;
    Pa[(size_t)(((o >> 4) * 32) + (c >> 3)) * 128 + (o & 15) * 8 + (c & 7)] = f2bf(pw[idx]);
}

// ---------------- K5: depthwise 7x7, column-strip threads, fp32 LDS ----------------
// 8 channels x 16 output rows per block. thread = (ch, col), 16-row column strip.
// Ug layout: [b][p>>4][cb][p&15][ch]  (identical to round-2, pw reads it unchanged)
__global__ __launch_bounds__(512, 4) void dw_kernel(const float* __restrict__ x,
                                                    const float* __restrict__ fused,
                                                    ushort* __restrict__ Ug) {
    __shared__ __align__(16) char smem[52352];
    float*  xs  = (float*)smem;              // 8 ch x 22 rows x 72 cols fp32 = 50688 B
    ushort* Us  = (ushort*)smem;             // 16 KB out staging, aliases xs (dead)
    float*  wsm = (float*)(smem + 50688);    // 8 x 52 floats = 1664 B

    const int strip = blockIdx.x;            // 0..3  (16-row strips)
    const int cb    = blockIdx.y;            // 0..31
    const int b     = blockIdx.z;
    const int tid   = threadIdx.x;           // 0..511
    const int c0    = cb * 8;
    const int r0    = strip * 16;

    // ---- stage x halo tile (rows r0-3 .. r0+18, cols -3..68, zero-padded) ----
    for (int i = tid; i < 8 * 22 * 72; i += 512) {
        int ch  = i / 1584;
        int r2  = i - ch * 1584;
        int row = r2 / 72;
        int col = r2 - row * 72;
        int gr = r0 + row - 3, gc = col - 3;
        float v = 0.f;
        if (((unsigned)gr < 64u) && ((unsigned)gc < 64u))
            v = x[(((size_t)b * C_ + c0 + ch) << 12) + (gr << 6) + gc];
        xs[i] = v;
    }
    for (int i = tid; i < 8 * KK_; i += 512) {
        int ch = i / KK_, t = i - ch * KK_;
        wsm[ch * 52 + t] = fused[((size_t)b * C_ + c0 + ch) * KK_ + t];
    }
    __syncthreads();

    const int ch = tid >> 6;    // one channel per wave -> broadcast weight reads
    const int c  = tid & 63;

    float wk[49];
#pragma unroll
    for (int q = 0; q < 12; q++) {
        float4 w4 = *(const float4*)&wsm[ch * 52 + q * 4];
        wk[q * 4 + 0] = w4.x; wk[q * 4 + 1] = w4.y;
        wk[q * 4 + 2] = w4.z; wk[q * 4 + 3] = w4.w;
    }
    wk[48] = wsm[ch * 52 + 48];

    float acc[16];
#pragma unroll
    for (int o = 0; o < 16; o++) acc[o] = 0.f;

    const float* xcol = xs + ch * 1584 + c;
#pragma unroll
    for (int ir = 0; ir < 22; ir++) {
        float x7[7];
#pragma unroll
        for (int j = 0; j < 7; j++) x7[j] = xcol[ir * 72 + j];   // lanes consecutive: conflict-free
        const int olo = (ir - 6 < 0) ? 0 : ir - 6;
        const int ohi = (ir < 15) ? ir : 15;
#pragma unroll
        for (int o = olo; o <= ohi; o++) {
            const int ki = ir - o;
#pragma unroll
            for (int j = 0; j < 7; j++)
                acc[o] = fmaf(x7[j], wk[ki * 7 + j], acc[o]);
        }
    }
    __syncthreads();   // all xs reads done; safe to alias with Us

    // ---- stage bf16 outputs: chunk q = o*4 + (c>>4), slot = (c&15)*8 + ch ----
#pragma unroll
    for (int o = 0; o < 16; o++)
        Us[(o * 4 + (c >> 4)) * 128 + (c & 15) * 8 + ch] = f2bf(acc[o]);
    __syncthreads();

    // ---- coalesced writeout: 64 chunks x 256B ----
    for (int t = tid; t < 1024; t += 512) {
        int q = t >> 4, part = t & 15;
        int o = q >> 2, cg = q & 3;
        size_t e = ((((size_t)b * 256) + (size_t)((r0 + o) * 4 + cg)) * 32 + cb) * 128
                   + (size_t)part * 8;
        *(uint4*)(Ug + e) = *(const uint4*)(Us + q * 128 + part * 8);
    }
}

// ---------------- K6: pointwise GEMM, bf16 MFMA. BM=256 BN=128 BK=64 ----------------
#define GLDS16(gp, lp) __builtin_amdgcn_global_load_lds(\
    (const __attribute__((address_space(1))) uint32_t*)(gp), \
    (__attribute__((address_space(3))) uint32_t*)(lp), 16, 0, 0)

__global__ __launch_bounds__(256, 2) void pw_kernel(const ushort* __restrict__ Pa,
                                                    const ushort* __restrict__ Ug,
                                                    float* __restrict__ Y) {
    __shared__ ushort As[16384];   // 256o x 64k: [obl(16)][kbl(8)][16][8]
    __shared__ ushort Bs[8192];    // 128p x 64k: [pgl(8)][kbl(8)][16][8]
    const int pb   = blockIdx.x;   // 0..31
    const int b    = blockIdx.y;
    const int tid  = threadIdx.x;
    const int w    = tid >> 6;
    const int lane = tid & 63;
    const int oi   = lane & 15;
    const int kq   = lane >> 4;    // 0..3

    f32x4 acc[4][8];
#pragma unroll
    for (int mi = 0; mi < 4; mi++)
#pragma unroll
        for (int ni = 0; ni < 8; ni++)
            acc[mi][ni] = (f32x4){0.f, 0.f, 0.f, 0.f};

    const size_t ubase = (((size_t)b * 256) + (size_t)pb * 8) * 32 * 128;

    for (int kk = 0; kk < 4; kk++) {
        __syncthreads();
        for (int q = w; q < 48; q += 4) {
            const ushort* src; ushort* dst;
            if (q < 32) {
                int obl = q >> 1, half = q & 1;
                src = Pa + (obl * 32 + kk * 8) * 128 + half * 512;
                dst = As + obl * 1024 + half * 512;
            } else {
                int idx = q - 32, pgl = idx >> 1, half = idx & 1;
                src = Ug + ubase + ((size_t)pgl * 32 + kk * 8) * 128 + half * 512;
                dst = Bs + pgl * 1024 + half * 512;
            }
            GLDS16(src + lane * 8, dst);
        }
        asm volatile("s_waitcnt vmcnt(0)" ::: "memory");
        __syncthreads();

        const int abase = w * 4096 + kq * 128 + oi * 8;
        const int bbase = kq * 128 + oi * 8;
#pragma unroll
        for (int ks = 0; ks < 2; ks++) {
            short8 af[4], bf[8];
#pragma unroll
            for (int mi = 0; mi < 4; mi++)
                af[mi] = *(const short8*)&As[abase + mi * 1024 + ks * 512];
#pragma unroll
            for (int ni = 0; ni < 8; ni++)
                bf[ni] = *(const short8*)&Bs[bbase + ni * 1024 + ks * 512];
#pragma unroll
            for (int mi = 0; mi < 4; mi++)
#pragma unroll
                for (int ni = 0; ni < 8; ni++)
                    acc[mi][ni] = __builtin_amdgcn_mfma_f32_16x16x32_bf16(
                        af[mi], bf[ni], acc[mi][ni], 0, 0, 0);
        }
    }
    float* yb = Y + ((size_t)b << 20);
    const int p0 = pb * 128;
#pragma unroll
    for (int mi = 0; mi < 4; mi++) {
#pragma unroll
        for (int ni = 0; ni < 8; ni++) {
            int p = p0 + ni * 16 + oi;
#pragma unroll
            for (int r = 0; r < 4; r++) {
                int o = w * 64 + mi * 16 + kq * 4 + r;
                yb[(size_t)o * HW_ + p] = acc[mi][ni][r];
            }
        }
    }
}

extern "C" void kernel_launch(void* const* d_in, const int* in_sizes, int n_in,
                              void* d_out, int out_size, void* d_ws, size_t ws_size,
                              hipStream_t stream) {
    const float* x  = (const float*)d_in[0];
    const float* dw = (const float*)d_in[1];
    const float* pw = (const float*)d_in[2];
    const float* w1 = (const float*)d_in[3];
    const float* b1 = (const float*)d_in[4];
    const float* w2 = (const float*)d_in[5];
    const float* b2 = (const float*)d_in[6];
    float* out = (float*)d_out;

    char* ws = (char*)d_ws;
    float*  pooled = (float*)(ws);                    // 16384 B
    float*  h      = (float*)(ws + 16384);            // 4096 B
    float*  fused  = (float*)(ws + 20480);            // 802816 B
    ushort* Pa     = (ushort*)(ws + 823296);          // 131072 B
    ushort* Ug     = (ushort*)(ws + 1048576);         // 33554432 B

    hipLaunchKernelGGL(pool_kernel, dim3(B_ * C_), dim3(256), 0, stream, x, pooled);
    hipLaunchKernelGGL(mlp_kernel,  dim3(B_), dim3(64), 0, stream, pooled, w1, b1, h);
    hipLaunchKernelGGL(genw_kernel, dim3(49), dim3(256), 0, stream, h, w2, b2, dw, fused);
    hipLaunchKernelGGL(prep_kernel, dim3(256), dim3(256), 0, stream, pw, Pa);
    hipLaunchKernelGGL(dw_kernel,   dim3(4, 32, B_), dim3(512), 0, stream, x, fused, Ug);
    hipLaunchKernelGGL(pw_kernel,   dim3(32, B_), dim3(256), 0, stream, Pa, Ug, out);
}

// Round 4
// 100.906 us; speedup vs baseline: 2.3802x; 1.0700x over previous
//
#include <hip/hip_runtime.h>
#include <math.h>
#include <stdint.h>

typedef __attribute__((ext_vector_type(8))) short short8;
typedef __attribute__((ext_vector_type(4))) float f32x4;

#define B_  16
#define C_  256
#define HW_ 4096
#define KK_ 49
#define CR_ 64

__device__ __forceinline__ ushort f2bf(float f) {
    union { float f; uint32_t u; } v; v.f = f;
    uint32_t r = (v.u + 0x7FFFu + ((v.u >> 16) & 1u)) >> 16;
    return (ushort)r;
}

// ---------------- K1: global average pool ----------------
__global__ __launch_bounds__(256) void pool_kernel(const float* __restrict__ x,
                                                   float* __restrict__ pooled) {
    int bc = blockIdx.x;
    const float4* p4 = (const float4*)(x + (size_t)bc * HW_);
    float s = 0.f;
    for (int i = threadIdx.x; i < HW_ / 4; i += 256) {
        float4 v = p4[i];
        s += (v.x + v.y) + (v.z + v.w);
    }
#pragma unroll
    for (int off = 32; off > 0; off >>= 1) s += __shfl_down(s, off);
    __shared__ float red[4];
    if ((threadIdx.x & 63) == 0) red[threadIdx.x >> 6] = s;
    __syncthreads();
    if (threadIdx.x == 0)
        pooled[bc] = (red[0] + red[1] + red[2] + red[3]) * (1.f / HW_);
}

// ---------------- K2: h = gelu(pooled @ w1^T + b1) ----------------
__global__ __launch_bounds__(64) void mlp_kernel(const float* __restrict__ pooled,
                                                 const float* __restrict__ w1,
                                                 const float* __restrict__ b1,
                                                 float* __restrict__ h) {
    int b = blockIdx.x;
    int r = threadIdx.x;
    __shared__ float pr[C_];
    for (int i = r; i < C_; i += 64) pr[i] = pooled[b * C_ + i];
    __syncthreads();
    float acc = b1[r];
    const float* wr = w1 + (size_t)r * C_;
    for (int c = 0; c < C_; c += 4) {
        float4 wv = *(const float4*)(wr + c);
        acc += pr[c] * wv.x + pr[c + 1] * wv.y + pr[c + 2] * wv.z + pr[c + 3] * wv.w;
    }
    h[b * CR_ + r] = 0.5f * acc * (1.f + erff(acc * 0.70710678118654752f));
}

// ---------------- K3: fused[b,m] = dw[m] + b2[m] + h[b,:] @ w2[m,:] ----------------
__global__ __launch_bounds__(256) void genw_kernel(const float* __restrict__ h,
                                                   const float* __restrict__ w2,
                                                   const float* __restrict__ b2,
                                                   const float* __restrict__ dw,
                                                   float* __restrict__ fused) {
    __shared__ float hs[B_ * CR_];
    int m = blockIdx.x * 256 + threadIdx.x;
    for (int i = threadIdx.x; i < B_ * CR_; i += 256) hs[i] = h[i];
    float wrow[CR_];
    const float4* w4 = (const float4*)(w2 + (size_t)m * CR_);
#pragma unroll
    for (int i = 0; i < CR_ / 4; i++) {
        float4 v = w4[i];
        wrow[4 * i] = v.x; wrow[4 * i + 1] = v.y;
        wrow[4 * i + 2] = v.z; wrow[4 * i + 3] = v.w;
    }
    float base = b2[m] + dw[m];
    __syncthreads();
    for (int b = 0; b < B_; b++) {
        float acc = base;
        const float* hb = hs + b * CR_;
#pragma unroll
        for (int r = 0; r < CR_; r++) acc += hb[r] * wrow[r];
        fused[(size_t)b * (C_ * KK_) + m] = acc;
    }
}

// ---------------- K4: pack pw_weight fp32 [o][c] -> Pa bf16 [o/16][c/8][16][8] ----------------
__global__ __launch_bounds__(256) void prep_kernel(const float* __restrict__ pw,
                                                   ushort* __restrict__ Pa) {
    int idx = blockIdx.x * 256 + threadIdx.x;   // 65536
    int o = idx >> 8, c = idx & 255;
    Pa[(size_t)(((o >> 4) * 32) + (c >> 3)) * 128 + (o & 15) * 8 + (c & 7)] = f2bf(pw[idx]);
}

// ---------------- K5: depthwise 7x7, column-strip threads, weights in SGPRs ----------------
// 8 channels x 16 output rows per block; wave = channel; thread = column strip.
// Ug layout: [b][p>>4][cb][p&15][c&7] bf16
__global__ __launch_bounds__(512, 4) void dw_kernel(const float* __restrict__ x,
                                                    const float* __restrict__ fused,
                                                    ushort* __restrict__ Ug) {
    __shared__ __align__(16) float xs[8 * 22 * 72];   // 50688 B; Us (16 KB) aliases it later
    ushort* Us = (ushort*)xs;

    const int strip = blockIdx.x;            // 0..3
    const int cb    = blockIdx.y;            // 0..31
    const int b     = blockIdx.z;
    const int tid   = threadIdx.x;           // 0..511
    const int wid   = tid >> 6;              // channel within group (wave-uniform)
    const int lane  = tid & 63;
    const int c0    = cb * 8;
    const int r0    = strip * 16;

    // ---- stage x: wave wid loads channel wid; rows r0-3 .. r0+18 ----
    {
        const float* xp = x + (((size_t)(b * C_ + c0 + wid)) << 12);
        float* xd = xs + wid * 1584;
#pragma unroll
        for (int row = 0; row < 22; row++) {
            int gr = r0 + row - 3;           // wave-uniform -> scalar branch
            float v = 0.f;
            if ((unsigned)gr < 64u) v = xp[(gr << 6) + lane];
            xd[row * 72 + 3 + lane] = v;
        }
        // edge columns 0..2 and 67..71 are always zero (22 rows x 8 cols)
        for (int j = lane; j < 176; j += 64) {
            int row = j >> 3, e = j & 7;
            int col = (e < 3) ? e : (64 + e);
            xd[row * 72 + col] = 0.f;
        }
    }

    // ---- weights -> SGPRs (wave-uniform channel): one load + 49 readlanes ----
    float wk[49];
    {
        const float* fp = fused + (((size_t)b * C_) + c0 + wid) * KK_;
        float v = (lane < KK_) ? fp[lane] : 0.f;
        int vi = __float_as_int(v);
#pragma unroll
        for (int t = 0; t < 49; t++)
            wk[t] = __int_as_float(__builtin_amdgcn_readlane(vi, t));
    }
    __syncthreads();

    const int c = lane;
    float acc[16];
#pragma unroll
    for (int o = 0; o < 16; o++) acc[o] = 0.f;

    const float* xcol = xs + wid * 1584 + c;
#pragma unroll
    for (int ir = 0; ir < 22; ir++) {
        float x7[7];
#pragma unroll
        for (int j = 0; j < 7; j++) x7[j] = xcol[ir * 72 + j];   // consecutive lanes: conflict-free
        const int olo = (ir - 6 < 0) ? 0 : ir - 6;
        const int ohi = (ir < 15) ? ir : 15;
#pragma unroll
        for (int o = olo; o <= ohi; o++) {
            const int ki = ir - o;
#pragma unroll
            for (int j = 0; j < 7; j++)
                acc[o] = fmaf(x7[j], wk[ki * 7 + j], acc[o]);     // SGPR weight operand
        }
    }
    __syncthreads();   // all xs reads done; safe to alias with Us

    // ---- stage bf16 outputs: chunk q = o*4 + (c>>4), slot = (c&15)*8 + ch ----
#pragma unroll
    for (int o = 0; o < 16; o++)
        Us[(o * 4 + (c >> 4)) * 128 + (c & 15) * 8 + wid] = f2bf(acc[o]);
    __syncthreads();

    // ---- coalesced writeout: 64 chunks x 256B ----
    for (int t = tid; t < 1024; t += 512) {
        int q = t >> 4, part = t & 15;
        int o = q >> 2, cg = q & 3;
        size_t e = ((((size_t)b * 256) + (size_t)((r0 + o) * 4 + cg)) * 32 + cb) * 128
                   + (size_t)part * 8;
        *(uint4*)(Ug + e) = *(const uint4*)(Us + q * 128 + part * 8);
    }
}

// ---------------- K6: pointwise GEMM, bf16 MFMA, BK=32 ping-pong pipeline ----------------
#define GLDS16(gp, lp) __builtin_amdgcn_global_load_lds(\
    (const __attribute__((address_space(1))) uint32_t*)(gp), \
    (__attribute__((address_space(3))) uint32_t*)(lp), 16, 0, 0)

__global__ __launch_bounds__(256, 2) void pw_kernel(const ushort* __restrict__ Pa,
                                                    const ushort* __restrict__ Ug,
                                                    float* __restrict__ Y) {
    __shared__ ushort As[2][8192];   // per buf: 256o x 32k  [obl(16)][kb(4)][16][8]
    __shared__ ushort Bs[2][4096];   // per buf: 128p x 32k  [pgl(8)][kb(4)][16][8]
    const int pb   = blockIdx.x;     // 0..31
    const int b    = blockIdx.y;
    const int tid  = threadIdx.x;
    const int w    = tid >> 6;
    const int lane = tid & 63;
    const int oi   = lane & 15;
    const int kq   = lane >> 4;      // 0..3

    f32x4 acc[4][8];
#pragma unroll
    for (int mi = 0; mi < 4; mi++)
#pragma unroll
        for (int ni = 0; ni < 8; ni++)
            acc[mi][ni] = (f32x4){0.f, 0.f, 0.f, 0.f};

    const size_t ubase = (((size_t)b * 256) + (size_t)pb * 8) * 32 * 128;

    // stage(buf, kb0): 24 x 1KB chunks, 6 per wave
#define STAGE(BUF, KB0)                                                          \
    for (int q = w; q < 24; q += 4) {                                            \
        const ushort* src; ushort* dst;                                          \
        if (q < 16) { src = Pa + ((size_t)q * 32 + (KB0)) * 128;                 \
                      dst = &As[BUF][q * 512]; }                                 \
        else { int pg = q - 16;                                                  \
               src = Ug + ubase + ((size_t)pg * 32 + (KB0)) * 128;               \
               dst = &Bs[BUF][pg * 512]; }                                       \
        GLDS16(src + lane * 8, dst);                                             \
    }

    STAGE(0, 0)

#pragma unroll
    for (int ki = 0; ki < 8; ki++) {
        const int buf = ki & 1;
        if (ki < 7) {
            STAGE(buf ^ 1, (ki + 1) * 4)
            asm volatile("s_waitcnt vmcnt(6)" ::: "memory");   // own prev 6 done; next 6 in flight
        } else {
            asm volatile("s_waitcnt vmcnt(0)" ::: "memory");
        }
        __builtin_amdgcn_s_barrier();
        __builtin_amdgcn_sched_barrier(0);

        short8 af[4], bf[8];
#pragma unroll
        for (int mi = 0; mi < 4; mi++)
            af[mi] = *(const short8*)&As[buf][(w * 4 + mi) * 512 + kq * 128 + oi * 8];
#pragma unroll
        for (int ni = 0; ni < 8; ni++)
            bf[ni] = *(const short8*)&Bs[buf][ni * 512 + kq * 128 + oi * 8];
#pragma unroll
        for (int mi = 0; mi < 4; mi++)
#pragma unroll
            for (int ni = 0; ni < 8; ni++)
                acc[mi][ni] = __builtin_amdgcn_mfma_f32_16x16x32_bf16(
                    af[mi], bf[ni], acc[mi][ni], 0, 0, 0);

        __builtin_amdgcn_s_barrier();
        __builtin_amdgcn_sched_barrier(0);
    }

    float* yb = Y + ((size_t)b << 20);
    const int p0 = pb * 128;
#pragma unroll
    for (int mi = 0; mi < 4; mi++) {
#pragma unroll
        for (int ni = 0; ni < 8; ni++) {
            int p = p0 + ni * 16 + oi;
#pragma unroll
            for (int r = 0; r < 4; r++) {
                int o = w * 64 + mi * 16 + kq * 4 + r;
                yb[(size_t)o * HW_ + p] = acc[mi][ni][r];
            }
        }
    }
#undef STAGE
}

extern "C" void kernel_launch(void* const* d_in, const int* in_sizes, int n_in,
                              void* d_out, int out_size, void* d_ws, size_t ws_size,
                              hipStream_t stream) {
    const float* x  = (const float*)d_in[0];
    const float* dw = (const float*)d_in[1];
    const float* pw = (const float*)d_in[2];
    const float* w1 = (const float*)d_in[3];
    const float* b1 = (const float*)d_in[4];
    const float* w2 = (const float*)d_in[5];
    const float* b2 = (const float*)d_in[6];
    float* out = (float*)d_out;

    char* ws = (char*)d_ws;
    float*  pooled = (float*)(ws);                    // 16384 B
    float*  h      = (float*)(ws + 16384);            // 4096 B
    float*  fused  = (float*)(ws + 20480);            // 802816 B
    ushort* Pa     = (ushort*)(ws + 823296);          // 131072 B
    ushort* Ug     = (ushort*)(ws + 1048576);         // 33554432 B

    hipLaunchKernelGGL(pool_kernel, dim3(B_ * C_), dim3(256), 0, stream, x, pooled);
    hipLaunchKernelGGL(mlp_kernel,  dim3(B_), dim3(64), 0, stream, pooled, w1, b1, h);
    hipLaunchKernelGGL(genw_kernel, dim3(49), dim3(256), 0, stream, h, w2, b2, dw, fused);
    hipLaunchKernelGGL(prep_kernel, dim3(256), dim3(256), 0, stream, pw, Pa);
    hipLaunchKernelGGL(dw_kernel,   dim3(4, 32, B_), dim3(512), 0, stream, x, fused, Ug);
    hipLaunchKernelGGL(pw_kernel,   dim3(32, B_), dim3(256), 0, stream, Pa, Ug, out);
}